// Round 6
// baseline (288.729 us; speedup 1.0000x reference)
//
#include <hip/hip_runtime.h>

#define DIM   1024
#define NQKV  3072
#define SEQ   2048
#define HEADS 16
#define DHEAD 64
#define M_TOT 4096   // batch(2) * seq(2048)

typedef __bf16 bf16;
typedef __bf16 bf16x8 __attribute__((ext_vector_type(8)));
typedef float  f32x4  __attribute__((ext_vector_type(4)));

typedef const __attribute__((address_space(1))) unsigned int gu32;
typedef __attribute__((address_space(3))) unsigned int su32;

static __device__ __forceinline__ unsigned short f2b(float f) {
    bf16 h = (bf16)f;
    return __builtin_bit_cast(unsigned short, h);
}

// ---------------- kernel 1: fused prep (cast x -> bf16 | transpose+scale W) ----------------
// blocks [0, 4096): cast x.  blocks [4096, 7168): transpose W.
// W scale = DHEAD^-0.5 * log2(e) folded into Q columns: attention uses raw exp2.
#define CAST_BLOCKS (M_TOT * DIM / (256 * 4))
__global__ void prep_kernel(const float* __restrict__ x,
                            unsigned short* __restrict__ xb,
                            const float* __restrict__ W,
                            unsigned short* __restrict__ Wt) {
    __shared__ float tile[32][33];
    const int id  = blockIdx.x;
    const int tid = threadIdx.x;
    if (id < CAST_BLOCKS) {
        int i = (id * 256 + tid) * 4;
        float4 v = *(const float4*)(x + i);
        ushort4 o;
        o.x = f2b(v.x); o.y = f2b(v.y); o.z = f2b(v.z); o.w = f2b(v.w);
        *(ushort4*)(xb + i) = o;
    } else {
        int t  = id - CAST_BLOCKS;          // 0..3071
        int nb = t % (NQKV / 32);           // N tile
        int kb = t / (NQKV / 32);           // K tile
        int tx = tid & 31, ty0 = tid >> 5;  // 32x8
        for (int ty = ty0; ty < 32; ty += 8)
            tile[ty][tx] = W[(size_t)(kb*32 + ty)*NQKV + nb*32 + tx];
        __syncthreads();
        for (int ty = ty0; ty < 32; ty += 8) {
            int n = nb*32 + ty;
            float s = (n < 1024) ? 0.18033688f : 1.0f;   // 0.125 * 1.44269504
            Wt[(size_t)n*DIM + kb*32 + tx] = f2b(tile[tx][ty] * s);
        }
    }
}

// ---------------- kernel 2: QKV GEMM, LDS-restaged coalesced epilogue ----------------
#define LDC 136
__global__ __launch_bounds__(256) void qkv_gemm_kernel(
    const unsigned short* __restrict__ A,
    const unsigned short* __restrict__ Bt,
    unsigned short* __restrict__ Qw,
    unsigned short* __restrict__ Kw,
    unsigned short* __restrict__ Vtw)
{
    __shared__ __align__(16) unsigned char smem[128 * LDC * 2];   // 34816 B
    unsigned short* As = (unsigned short*)smem;
    unsigned short* Bs = (unsigned short*)(smem + 16384);
    unsigned short* Cs = (unsigned short*)smem;

    const int tid  = threadIdx.x;
    const int m0   = blockIdx.y * 128;
    const int n0   = blockIdx.x * 128;
    const int w    = tid >> 6;
    const int lane = tid & 63;
    const int l16  = lane & 15;
    const int quad = lane >> 4;
    const int wm   = (w >> 1) * 64;
    const int wn   = (w & 1) * 64;
    const int srow = lane >> 3;
    const int scol = (lane & 7) * 8;

    f32x4 acc[4][4];
    const f32x4 fzero = {0.f, 0.f, 0.f, 0.f};
    for (int i = 0; i < 4; i++)
        for (int j = 0; j < 4; j++) acc[i][j] = fzero;

    const unsigned short* Ag = A  + (size_t)(m0 + w * 32 + srow) * DIM + scol;
    const unsigned short* Bg = Bt + (size_t)(n0 + w * 32 + srow) * DIM + scol;

    for (int kt = 0; kt < DIM; kt += 64) {
        #pragma unroll
        for (int j = 0; j < 4; j++) {
            __builtin_amdgcn_global_load_lds((gu32*)(Ag + kt + (size_t)j * 8 * DIM),
                                             (su32*)&As[(w * 32 + j * 8) * 64], 16, 0, 0);
            __builtin_amdgcn_global_load_lds((gu32*)(Bg + kt + (size_t)j * 8 * DIM),
                                             (su32*)&Bs[(w * 32 + j * 8) * 64], 16, 0, 0);
        }
        __syncthreads();
        #pragma unroll
        for (int s = 0; s < 2; s++) {
            bf16x8 af[4], bfr[4];
            #pragma unroll
            for (int i = 0; i < 4; i++) {
                af[i]  = *(const bf16x8*)(&As[(wm + i * 16 + l16) * 64 + s * 32 + quad * 8]);
                bfr[i] = *(const bf16x8*)(&Bs[(wn + i * 16 + l16) * 64 + s * 32 + quad * 8]);
            }
            #pragma unroll
            for (int i = 0; i < 4; i++)
                #pragma unroll
                for (int j = 0; j < 4; j++)
                    acc[i][j] = __builtin_amdgcn_mfma_f32_16x16x32_bf16(af[i], bfr[j], acc[i][j], 0, 0, 0);
        }
        __syncthreads();
    }

    const int part = n0 >> 10;
    const int h0   = (n0 & 1023) >> 6;
    const int b    = m0 >> 11;
    const int np0  = m0 & 2047;

    if (part < 2) {
        #pragma unroll
        for (int i = 0; i < 4; i++)
            #pragma unroll
            for (int j = 0; j < 4; j++)
                #pragma unroll
                for (int r = 0; r < 4; r++)
                    Cs[(wm + i * 16 + quad * 4 + r) * LDC + wn + j * 16 + l16] = f2b(acc[i][j][r]);
        __syncthreads();
        unsigned short* dst = (part == 0) ? Qw : Kw;
        #pragma unroll
        for (int pass = 0; pass < 8; pass++) {
            int mi = pass * 16 + (tid >> 4);
            int ci = (tid & 15) * 8;
            uint4 v = *(const uint4*)&Cs[mi * LDC + ci];
            int bh = b * HEADS + h0 + (ci >> 6);
            *(uint4*)&dst[((size_t)bh * SEQ + np0 + mi) * DHEAD + (ci & 63)] = v;
        }
    } else {
        #pragma unroll
        for (int i = 0; i < 4; i++)
            #pragma unroll
            for (int j = 0; j < 4; j++) {
                ushort4 pk;
                pk.x = f2b(acc[i][j][0]); pk.y = f2b(acc[i][j][1]);
                pk.z = f2b(acc[i][j][2]); pk.w = f2b(acc[i][j][3]);
                *(ushort4*)&Cs[(wn + j * 16 + l16) * LDC + wm + i * 16 + quad * 4] = pk;
            }
        __syncthreads();
        #pragma unroll
        for (int pass = 0; pass < 8; pass++) {
            int ci = pass * 16 + (tid >> 4);
            int mi = (tid & 15) * 8;
            uint4 v = *(const uint4*)&Cs[ci * LDC + mi];
            int bh = b * HEADS + h0 + (ci >> 6);
            *(uint4*)&Vtw[((size_t)bh * DHEAD + (ci & 63)) * SEQ + np0 + mi] = v;
        }
    }
}

// ---------------- kernel 3: flash attention + residual ----------------
// 128-key tiles. Key-permuted S^T: key(ki,m) = (ki>>1)*32 + (m>>2)*8 + (ki&1)*4 + (m&3)
// makes QK C-regs the PV A-frags in-register. Denominator via ones-MFMA.
// NOTE: no min-waves launch bound — R5's (256,4) capped VGPRs and caused
// 260 MB of scratch spill traffic (WRITE_SIZE counter). LDS already sets occupancy.
#define LDK 72
#define LDP 136
__global__ __launch_bounds__(256) void attn_kernel(
    const unsigned short* __restrict__ Qw,
    const unsigned short* __restrict__ Kw,
    const unsigned short* __restrict__ Vtw,
    const float* __restrict__ x,
    float* __restrict__ out)
{
    __shared__ __align__(16) unsigned short Ks[128 * LDK];   // [key][d]
    __shared__ __align__(16) unsigned short Vs[64 * LDP];    // V^T: [d][key 0..127]
    const int id  = blockIdx.x;
    const int qt  = id >> 5;
    const int bh  = ((id & 7) << 2) | ((id >> 3) & 3);       // 4 bh per XCD
    const int tid = threadIdx.x;
    const int w   = tid >> 6, lane = tid & 63;
    const int l16 = lane & 15, quad = lane >> 4;

    const unsigned short* Qbase = Qw + ((size_t)bh * SEQ + qt * 64 + w * 16 + l16) * DHEAD;
    bf16x8 qf[2];
    qf[0] = *(const bf16x8*)(Qbase + quad * 8);
    qf[1] = *(const bf16x8*)(Qbase + 32 + quad * 8);

    const int prow = ((l16 >> 2) << 3) | (l16 & 3);

    bf16x8 ones;
    #pragma unroll
    for (int j = 0; j < 8; j++) ones[j] = (bf16)1.0f;

    f32x4 o[4], dsum;
    const f32x4 fzero = {0.f, 0.f, 0.f, 0.f};
    #pragma unroll
    for (int d = 0; d < 4; d++) o[d] = fzero;
    dsum = fzero;

    const unsigned short* Kg = Kw  + (size_t)bh * SEQ * DHEAD;
    const unsigned short* Vg = Vtw + (size_t)bh * DHEAD * SEQ;

    const int kr = tid >> 3, kc = (tid & 7) * 8;    // K chunks: rows kr+32i
    const int vr = tid >> 4, vc = (tid & 15) * 8;   // V chunks: rows vr+16i

    uint4 kreg[4], vreg[4];
    #pragma unroll
    for (int i = 0; i < 4; i++) {
        kreg[i] = *(const uint4*)(Kg + (size_t)(kr + 32 * i) * DHEAD + kc);
        vreg[i] = *(const uint4*)(Vg + (size_t)(vr + 16 * i) * SEQ + vc);
    }

    for (int t = 0; t < SEQ / 128; t++) {
        __syncthreads();
        #pragma unroll
        for (int i = 0; i < 4; i++) {
            *(uint4*)&Ks[(kr + 32 * i) * LDK + kc] = kreg[i];
            *(uint4*)&Vs[(vr + 16 * i) * LDP + vc] = vreg[i];
        }
        int kvn = ((t + 1) & (SEQ / 128 - 1)) * 128;
        #pragma unroll
        for (int i = 0; i < 4; i++) {
            kreg[i] = *(const uint4*)(Kg + (size_t)(kvn + kr + 32 * i) * DHEAD + kc);
            vreg[i] = *(const uint4*)(Vg + (size_t)(vr + 16 * i) * SEQ + kvn + vc);
        }
        __syncthreads();

        // S^T = K_perm · Q^T  (8 key subtiles of 16)
        f32x4 sacc[8];
        #pragma unroll
        for (int ki = 0; ki < 8; ki++) sacc[ki] = fzero;
        #pragma unroll
        for (int s = 0; s < 2; s++)
            #pragma unroll
            for (int ki = 0; ki < 8; ki++) {
                bf16x8 kf = *(const bf16x8*)(
                    &Ks[((ki >> 1) * 32 + prow + (ki & 1) * 4) * LDK + s * 32 + quad * 8]);
                sacc[ki] = __builtin_amdgcn_mfma_f32_16x16x32_bf16(kf, qf[s], sacc[ki], 0, 0, 0);
            }

        // exp2 -> P A-frags in-register; denom + PV on the MFMA pipe
        #pragma unroll
        for (int s = 0; s < 4; s++) {
            bf16x8 pf;
            #pragma unroll
            for (int half = 0; half < 2; half++) {
                int ki = 2 * s + half;
                #pragma unroll
                for (int r = 0; r < 4; r++)
                    pf[half * 4 + r] = (bf16)__builtin_amdgcn_exp2f(sacc[ki][r]);
            }
            dsum = __builtin_amdgcn_mfma_f32_16x16x32_bf16(pf, ones, dsum, 0, 0, 0);
            #pragma unroll
            for (int d = 0; d < 4; d++) {
                bf16x8 vf = *(const bf16x8*)(&Vs[(d * 16 + l16) * LDP + s * 32 + quad * 8]);
                o[d] = __builtin_amdgcn_mfma_f32_16x16x32_bf16(pf, vf, o[d], 0, 0, 0);
            }
        }
    }

    // dsum[r] = denominator of query quad*4+r (replicated across l16)
    float lr[4];
    #pragma unroll
    for (int r = 0; r < 4; r++) lr[r] = __builtin_amdgcn_rcpf(dsum[r]);

    const int b = bh >> 4, h = bh & 15;
    #pragma unroll
    for (int di = 0; di < 4; di++)
        #pragma unroll
        for (int r = 0; r < 4; r++) {
            int np  = qt * 64 + w * 16 + quad * 4 + r;
            int col = h * 64 + di * 16 + l16;
            size_t g = ((size_t)(b * SEQ + np)) * DIM + col;
            out[g] = o[di][r] * lr[r] + x[g];
        }
}

extern "C" void kernel_launch(void* const* d_in, const int* in_sizes, int n_in,
                              void* d_out, int out_size, void* d_ws, size_t ws_size,
                              hipStream_t stream) {
    const float* x  = (const float*)d_in[0];   // [2,2048,1024]
    const float* Wq = (const float*)d_in[1];   // [1024,3072]
    float* out = (float*)d_out;

    unsigned short* xb = (unsigned short*)d_ws;                  // [4096][1024]
    unsigned short* Wt = xb + (size_t)M_TOT * DIM;               // [3072][1024]
    unsigned short* Qw = Wt + (size_t)NQKV * DIM;                // [32][2048][64]
    unsigned short* Kw = Qw + (size_t)32 * SEQ * DHEAD;          // [32][2048][64]
    unsigned short* Vt = Kw + (size_t)32 * SEQ * DHEAD;          // [32][64][2048]

    prep_kernel<<<CAST_BLOCKS + (NQKV / 32) * (DIM / 32), 256, 0, stream>>>(x, xb, Wq, Wt);
    qkv_gemm_kernel<<<dim3(NQKV / 128, M_TOT / 128), 256, 0, stream>>>(xb, Wt, Qw, Kw, Vt);
    attn_kernel<<<(SEQ / 64) * 32, 256, 0, stream>>>(Qw, Kw, Vt, x, out);
}

// Round 7
// 177.093 us; speedup vs baseline: 1.6304x; 1.6304x over previous
//
#include <hip/hip_runtime.h>

#define DIM   1024
#define NQKV  3072
#define SEQ   2048
#define HEADS 16
#define DHEAD 64
#define M_TOT 4096   // batch(2) * seq(2048)

typedef __bf16 bf16;
typedef __bf16 bf16x8 __attribute__((ext_vector_type(8)));
typedef float  f32x4  __attribute__((ext_vector_type(4)));

typedef const __attribute__((address_space(1))) unsigned int gu32;
typedef __attribute__((address_space(3))) unsigned int su32;

static __device__ __forceinline__ unsigned short f2b(float f) {
    bf16 h = (bf16)f;
    return __builtin_bit_cast(unsigned short, h);
}

// ---------------- kernel 1: fused prep (cast x -> bf16 | transpose+scale W) ----------------
#define CAST_BLOCKS (M_TOT * DIM / (256 * 4))
__global__ void prep_kernel(const float* __restrict__ x,
                            unsigned short* __restrict__ xb,
                            const float* __restrict__ W,
                            unsigned short* __restrict__ Wt) {
    __shared__ float tile[32][33];
    const int id  = blockIdx.x;
    const int tid = threadIdx.x;
    if (id < CAST_BLOCKS) {
        int i = (id * 256 + tid) * 4;
        float4 v = *(const float4*)(x + i);
        ushort4 o;
        o.x = f2b(v.x); o.y = f2b(v.y); o.z = f2b(v.z); o.w = f2b(v.w);
        *(ushort4*)(xb + i) = o;
    } else {
        int t  = id - CAST_BLOCKS;
        int nb = t % (NQKV / 32);
        int kb = t / (NQKV / 32);
        int tx = tid & 31, ty0 = tid >> 5;
        for (int ty = ty0; ty < 32; ty += 8)
            tile[ty][tx] = W[(size_t)(kb*32 + ty)*NQKV + nb*32 + tx];
        __syncthreads();
        for (int ty = ty0; ty < 32; ty += 8) {
            int n = nb*32 + ty;
            float s = (n < 1024) ? 0.18033688f : 1.0f;   // 0.125 * log2(e)
            Wt[(size_t)n*DIM + kb*32 + tx] = f2b(tile[tx][ty] * s);
        }
    }
}

// ---------------- kernel 2: QKV GEMM, LDS-restaged coalesced epilogue ----------------
#define LDC 136
__global__ __launch_bounds__(256) void qkv_gemm_kernel(
    const unsigned short* __restrict__ A,
    const unsigned short* __restrict__ Bt,
    unsigned short* __restrict__ Qw,
    unsigned short* __restrict__ Kw,
    unsigned short* __restrict__ Vtw)
{
    __shared__ __align__(16) unsigned char smem[128 * LDC * 2];   // 34816 B
    unsigned short* As = (unsigned short*)smem;
    unsigned short* Bs = (unsigned short*)(smem + 16384);
    unsigned short* Cs = (unsigned short*)smem;

    const int tid  = threadIdx.x;
    const int m0   = blockIdx.y * 128;
    const int n0   = blockIdx.x * 128;
    const int w    = tid >> 6;
    const int lane = tid & 63;
    const int l16  = lane & 15;
    const int quad = lane >> 4;
    const int wm   = (w >> 1) * 64;
    const int wn   = (w & 1) * 64;
    const int srow = lane >> 3;
    const int scol = (lane & 7) * 8;

    f32x4 acc[4][4];
    const f32x4 fzero = {0.f, 0.f, 0.f, 0.f};
    for (int i = 0; i < 4; i++)
        for (int j = 0; j < 4; j++) acc[i][j] = fzero;

    const unsigned short* Ag = A  + (size_t)(m0 + w * 32 + srow) * DIM + scol;
    const unsigned short* Bg = Bt + (size_t)(n0 + w * 32 + srow) * DIM + scol;

    for (int kt = 0; kt < DIM; kt += 64) {
        #pragma unroll
        for (int j = 0; j < 4; j++) {
            __builtin_amdgcn_global_load_lds((gu32*)(Ag + kt + (size_t)j * 8 * DIM),
                                             (su32*)&As[(w * 32 + j * 8) * 64], 16, 0, 0);
            __builtin_amdgcn_global_load_lds((gu32*)(Bg + kt + (size_t)j * 8 * DIM),
                                             (su32*)&Bs[(w * 32 + j * 8) * 64], 16, 0, 0);
        }
        __syncthreads();
        #pragma unroll
        for (int s = 0; s < 2; s++) {
            bf16x8 af[4], bfr[4];
            #pragma unroll
            for (int i = 0; i < 4; i++) {
                af[i]  = *(const bf16x8*)(&As[(wm + i * 16 + l16) * 64 + s * 32 + quad * 8]);
                bfr[i] = *(const bf16x8*)(&Bs[(wn + i * 16 + l16) * 64 + s * 32 + quad * 8]);
            }
            #pragma unroll
            for (int i = 0; i < 4; i++)
                #pragma unroll
                for (int j = 0; j < 4; j++)
                    acc[i][j] = __builtin_amdgcn_mfma_f32_16x16x32_bf16(af[i], bfr[j], acc[i][j], 0, 0, 0);
        }
        __syncthreads();
    }

    const int part = n0 >> 10;
    const int h0   = (n0 & 1023) >> 6;
    const int b    = m0 >> 11;
    const int np0  = m0 & 2047;

    if (part < 2) {
        #pragma unroll
        for (int i = 0; i < 4; i++)
            #pragma unroll
            for (int j = 0; j < 4; j++)
                #pragma unroll
                for (int r = 0; r < 4; r++)
                    Cs[(wm + i * 16 + quad * 4 + r) * LDC + wn + j * 16 + l16] = f2b(acc[i][j][r]);
        __syncthreads();
        unsigned short* dst = (part == 0) ? Qw : Kw;
        #pragma unroll
        for (int pass = 0; pass < 8; pass++) {
            int mi = pass * 16 + (tid >> 4);
            int ci = (tid & 15) * 8;
            uint4 v = *(const uint4*)&Cs[mi * LDC + ci];
            int bh = b * HEADS + h0 + (ci >> 6);
            *(uint4*)&dst[((size_t)bh * SEQ + np0 + mi) * DHEAD + (ci & 63)] = v;
        }
    } else {
        #pragma unroll
        for (int i = 0; i < 4; i++)
            #pragma unroll
            for (int j = 0; j < 4; j++) {
                ushort4 pk;
                pk.x = f2b(acc[i][j][0]); pk.y = f2b(acc[i][j][1]);
                pk.z = f2b(acc[i][j][2]); pk.w = f2b(acc[i][j][3]);
                *(ushort4*)&Cs[(wn + j * 16 + l16) * LDC + wm + i * 16 + quad * 4] = pk;
            }
        __syncthreads();
        #pragma unroll
        for (int pass = 0; pass < 8; pass++) {
            int ci = pass * 16 + (tid >> 4);
            int mi = (tid & 15) * 8;
            uint4 v = *(const uint4*)&Cs[ci * LDC + mi];
            int bh = b * HEADS + h0 + (ci >> 6);
            *(uint4*)&Vtw[((size_t)bh * DHEAD + (ci & 63)) * SEQ + np0 + mi] = v;
        }
    }
}

// ---------------- kernel 3: flash attention + residual ----------------
// R4 structure (64-key tiles, sacc[4] — the 128-key/sacc[8] variants spill to
// scratch: R5/R6 WRITE_SIZE 277/573 MB). Key-permuted S^T makes QK C-regs the
// PV A-frags in-register; denominator on the MFMA pipe via ones-vector.
#define LDK 72
__global__ __launch_bounds__(256) void attn_kernel(
    const unsigned short* __restrict__ Qw,
    const unsigned short* __restrict__ Kw,
    const unsigned short* __restrict__ Vtw,
    const float* __restrict__ x,
    float* __restrict__ out)
{
    __shared__ __align__(16) unsigned short Ks[64 * LDK];   // [key][d]
    __shared__ __align__(16) unsigned short Vs[64 * LDK];   // V^T: [d][key]
    const int id  = blockIdx.x;
    const int qt  = id >> 5;
    const int bh  = ((id & 7) << 2) | ((id >> 3) & 3);      // 4 bh per XCD
    const int tid = threadIdx.x;
    const int w   = tid >> 6, lane = tid & 63;
    const int l16 = lane & 15, quad = lane >> 4;

    const unsigned short* Qbase = Qw + ((size_t)bh * SEQ + qt * 64 + w * 16 + l16) * DHEAD;
    bf16x8 qf[2];
    qf[0] = *(const bf16x8*)(Qbase + quad * 8);
    qf[1] = *(const bf16x8*)(Qbase + 32 + quad * 8);

    const int prow = ((l16 >> 2) << 3) | (l16 & 3);

    bf16x8 ones;
    #pragma unroll
    for (int j = 0; j < 8; j++) ones[j] = (bf16)1.0f;

    f32x4 o[4], dsum;
    const f32x4 fzero = {0.f, 0.f, 0.f, 0.f};
    #pragma unroll
    for (int d = 0; d < 4; d++) o[d] = fzero;
    dsum = fzero;

    const unsigned short* Kg = Kw  + (size_t)bh * SEQ * DHEAD;
    const unsigned short* Vg = Vtw + (size_t)bh * DHEAD * SEQ;

    const int r0 = tid >> 3, c0 = (tid & 7) * 8;
    uint4 kreg0 = *(const uint4*)(Kg + (size_t)r0 * DHEAD + c0);
    uint4 kreg1 = *(const uint4*)(Kg + (size_t)(r0 + 32) * DHEAD + c0);
    uint4 vreg0 = *(const uint4*)(Vg + (size_t)r0 * SEQ + c0);
    uint4 vreg1 = *(const uint4*)(Vg + (size_t)(r0 + 32) * SEQ + c0);

    for (int t = 0; t < SEQ / 64; t++) {
        __syncthreads();
        *(uint4*)&Ks[r0 * LDK + c0]        = kreg0;
        *(uint4*)&Ks[(r0 + 32) * LDK + c0] = kreg1;
        *(uint4*)&Vs[r0 * LDK + c0]        = vreg0;
        *(uint4*)&Vs[(r0 + 32) * LDK + c0] = vreg1;
        int kvn = ((t + 1) & (SEQ / 64 - 1)) * 64;
        kreg0 = *(const uint4*)(Kg + (size_t)(kvn + r0) * DHEAD + c0);
        kreg1 = *(const uint4*)(Kg + (size_t)(kvn + r0 + 32) * DHEAD + c0);
        vreg0 = *(const uint4*)(Vg + (size_t)r0 * SEQ + kvn + c0);
        vreg1 = *(const uint4*)(Vg + (size_t)(r0 + 32) * SEQ + kvn + c0);
        __syncthreads();

        // S^T = K_perm · Q^T
        f32x4 sacc[4];
        #pragma unroll
        for (int ki = 0; ki < 4; ki++) sacc[ki] = fzero;
        #pragma unroll
        for (int s = 0; s < 2; s++)
            #pragma unroll
            for (int ki = 0; ki < 4; ki++) {
                bf16x8 kf = *(const bf16x8*)(
                    &Ks[((ki >> 1) * 32 + prow + (ki & 1) * 4) * LDK + s * 32 + quad * 8]);
                sacc[ki] = __builtin_amdgcn_mfma_f32_16x16x32_bf16(kf, qf[s], sacc[ki], 0, 0, 0);
            }

        // p = exp2(s); C-regs are the PV A-frags; denominator via ones-MFMA
        bf16x8 pf[2];
        #pragma unroll
        for (int s = 0; s < 2; s++)
            #pragma unroll
            for (int half = 0; half < 2; half++) {
                int ki = 2 * s + half;
                #pragma unroll
                for (int r = 0; r < 4; r++)
                    pf[s][half * 4 + r] = (bf16)__builtin_amdgcn_exp2f(sacc[ki][r]);
            }

        #pragma unroll
        for (int s = 0; s < 2; s++) {
            dsum = __builtin_amdgcn_mfma_f32_16x16x32_bf16(pf[s], ones, dsum, 0, 0, 0);
            #pragma unroll
            for (int d = 0; d < 4; d++) {
                bf16x8 vf = *(const bf16x8*)(&Vs[(d * 16 + l16) * LDK + s * 32 + quad * 8]);
                o[d] = __builtin_amdgcn_mfma_f32_16x16x32_bf16(pf[s], vf, o[d], 0, 0, 0);
            }
        }
    }

    // dsum[r] = denominator of query quad*4+r (replicated across l16 lanes)
    float lr[4];
    #pragma unroll
    for (int r = 0; r < 4; r++) lr[r] = __builtin_amdgcn_rcpf(dsum[r]);

    const int b = bh >> 4, h = bh & 15;
    #pragma unroll
    for (int di = 0; di < 4; di++)
        #pragma unroll
        for (int r = 0; r < 4; r++) {
            int np  = qt * 64 + w * 16 + quad * 4 + r;
            int col = h * 64 + di * 16 + l16;
            size_t g = ((size_t)(b * SEQ + np)) * DIM + col;
            out[g] = o[di][r] * lr[r] + x[g];
        }
}

extern "C" void kernel_launch(void* const* d_in, const int* in_sizes, int n_in,
                              void* d_out, int out_size, void* d_ws, size_t ws_size,
                              hipStream_t stream) {
    const float* x  = (const float*)d_in[0];   // [2,2048,1024]
    const float* Wq = (const float*)d_in[1];   // [1024,3072]
    float* out = (float*)d_out;

    unsigned short* xb = (unsigned short*)d_ws;                  // [4096][1024]
    unsigned short* Wt = xb + (size_t)M_TOT * DIM;               // [3072][1024]
    unsigned short* Qw = Wt + (size_t)NQKV * DIM;                // [32][2048][64]
    unsigned short* Kw = Qw + (size_t)32 * SEQ * DHEAD;          // [32][2048][64]
    unsigned short* Vt = Kw + (size_t)32 * SEQ * DHEAD;          // [32][64][2048]

    prep_kernel<<<CAST_BLOCKS + (NQKV / 32) * (DIM / 32), 256, 0, stream>>>(x, xb, Wq, Wt);
    qkv_gemm_kernel<<<dim3(NQKV / 128, M_TOT / 128), 256, 0, stream>>>(xb, Wt, Qw, Kw, Vt);
    attn_kernel<<<(SEQ / 64) * 32, 256, 0, stream>>>(Qw, Kw, Vt, x, out);
}